// Round 1
// baseline (640.361 us; speedup 1.0000x reference)
//
#include <hip/hip_runtime.h>
#include <stdint.h>

#define BATCH 32
#define NANCH 25200
#define CH 85
#define NCLS 80
#define TOPK 512
#define CONF_THRE 0.7f
#define NMS_THRE 0.45f
#define CLS_OFF 4096.0f

// ws layout: [0,128) int counters[32]; [128, 128+32*25200*8) uint64 candidate keys
// key64 = (conf_bits << 32) | (0xFFFFFFFF - anchor)  -> desc sort = conf desc, ties idx asc

__global__ __launch_bounds__(128) void scan_kernel(const float* __restrict__ pred,
                                                   unsigned long long* __restrict__ cand,
                                                   int* __restrict__ cnt) {
    __shared__ float tile[128 * CH];
    const int img = blockIdx.y;
    const int a0 = blockIdx.x * 128;
    const int na = min(128, NANCH - a0);
    const int tid = threadIdx.x;
    const float* src = pred + ((size_t)img * NANCH + a0) * CH;
    const int nf = na * CH;
    const int nv = nf >> 2;
    const float4* src4 = (const float4*)src;
    float4* t4 = (float4*)tile;
    for (int i = tid; i < nv; i += 128) t4[i] = src4[i];
    for (int i = (nv << 2) + tid; i < nf; i += 128) tile[i] = src[i];
    __syncthreads();

    float conf = -1.0f;
    if (tid < na) {
        const float* row = tile + tid * CH;
        float obj = row[4];
        float m = row[5];
        #pragma unroll
        for (int j = 1; j < NCLS; ++j) m = fmaxf(m, row[5 + j]);
        conf = obj * m;
    }
    const bool ok = (tid < na) && (conf >= CONF_THRE);
    const unsigned long long bm = __ballot(ok);
    if (bm) {
        const int lane = tid & 63;
        const int leader = __ffsll((unsigned long long)bm) - 1;
        int base = 0;
        if (lane == leader) base = atomicAdd(&cnt[img], __popcll(bm));
        base = __shfl(base, leader);
        if (ok) {
            const int rank = __popcll(bm & ((1ull << lane) - 1ull));
            const unsigned int anchor = (unsigned int)(a0 + tid);
            const unsigned long long key =
                ((unsigned long long)__float_as_uint(conf) << 32) |
                (unsigned long long)(0xFFFFFFFFu - anchor);
            cand[(size_t)img * NANCH + base + rank] = key;
        }
    }
}

__global__ __launch_bounds__(1024) void select_nms_kernel(const float* __restrict__ pred,
                                                          const unsigned long long* __restrict__ cand,
                                                          const int* __restrict__ cnt,
                                                          float* __restrict__ out) {
    __shared__ unsigned long long sbuf[1024];                 // 8 KB
    __shared__ float nx1[TOPK], ny1[TOPK], nx2[TOPK], ny2[TOPK], nar[TOPK]; // 10 KB
    __shared__ float detL[TOPK * 6];                          // 12 KB
    __shared__ union {
        unsigned long long mask[TOPK * 8];                    // 32 KB
        struct { unsigned int hist[256]; unsigned int sscan[256]; } h;
    } sh;
    __shared__ unsigned int s_cnt, s_pivot, s_rem;
    __shared__ unsigned char val[TOPK];
    __shared__ unsigned long long kw8[8];

    const int img = blockIdx.x;
    const int tid = threadIdx.x;
    const int lane = tid & 63;
    const int wv = tid >> 6;
    int n = cnt[img];
    if (n > NANCH) n = NANCH;
    const unsigned long long* cd = cand + (size_t)img * NANCH;

    // ---- radix select exact conf_bits of the 512th-largest (mantissa only; exp fixed=126) ----
    unsigned int T = 0u;
    if (n > TOPK) {
        unsigned int prefix = 0, pmask = 0, rem = TOPK;
        const int shifts[3] = {15, 7, 0};
        const int nbits[3] = {8, 8, 7};
        for (int p = 0; p < 3; ++p) {
            const int shv = shifts[p];
            const unsigned int nb = 1u << nbits[p];
            for (int i = tid; i < 256; i += 1024) sh.h.hist[i] = 0u;
            __syncthreads();
            for (int i = tid; i < n; i += 1024) {
                unsigned int c = (unsigned int)(cd[i] >> 32) & 0x7FFFFFu;
                if ((c & pmask) == prefix)
                    atomicAdd(&sh.h.hist[(c >> shv) & (nb - 1u)], 1u);
            }
            __syncthreads();
            if (tid < (int)nb) sh.h.sscan[tid] = sh.h.hist[tid];
            __syncthreads();
            for (unsigned int off = 1; off < nb; off <<= 1) {
                unsigned int v = 0;
                if (tid < (int)nb && tid + (int)off < (int)nb) v = sh.h.sscan[tid + off];
                __syncthreads();
                if (tid < (int)nb) sh.h.sscan[tid] += v;
                __syncthreads();
            }
            if (tid < (int)nb) {
                unsigned int s = sh.h.sscan[tid];
                unsigned int snx = (tid + 1 < (int)nb) ? sh.h.sscan[tid + 1] : 0u;
                if (s >= rem && snx < rem) { s_pivot = (unsigned int)tid; s_rem = rem - snx; }
            }
            __syncthreads();
            prefix |= s_pivot << shv;
            pmask |= (nb - 1u) << shv;
            rem = s_rem;
            __syncthreads();
        }
        T = 0x3F000000u | prefix;   // sign=0, exp=126, mantissa=prefix
    }

    // ---- compact conf >= T into sbuf ----
    if (tid == 0) s_cnt = 0u;
    __syncthreads();
    for (int i = tid; i < n; i += 1024) {
        const unsigned long long k = cd[i];
        if ((unsigned int)(k >> 32) >= T) {
            unsigned int pos = atomicAdd(&s_cnt, 1u);
            if (pos < 1024u) sbuf[pos] = k;
        }
    }
    __syncthreads();
    unsigned int mc = s_cnt; if (mc > 1024u) mc = 1024u;
    if (tid >= (int)mc) sbuf[tid] = 0ull;
    __syncthreads();

    // ---- bitonic sort 1024 desc ----
    for (int kk = 2; kk <= 1024; kk <<= 1) {
        for (int jj = kk >> 1; jj > 0; jj >>= 1) {
            const int ixj = tid ^ jj;
            if (ixj > tid) {
                const unsigned long long a = sbuf[tid], b = sbuf[ixj];
                const bool up = (tid & kk) == 0;
                if (up ? (a < b) : (a > b)) { sbuf[tid] = b; sbuf[ixj] = a; }
            }
            __syncthreads();
        }
    }

    // ---- gather: one wave per row ----
    for (int r = wv; r < TOPK; r += 16) {
        const unsigned long long key = sbuf[r];
        const float conf = __uint_as_float((unsigned int)(key >> 32));
        const bool okrow = conf >= CONF_THRE;
        float x1 = 0.f, y1 = 0.f, x2 = 0.f, y2 = 0.f, clsf = 0.f;
        if (okrow) {
            const unsigned int anchor = 0xFFFFFFFFu - (unsigned int)(key & 0xFFFFFFFFull);
            const float* row = pred + ((size_t)img * NANCH + anchor) * CH;
            float v = row[5 + lane];
            int ci = lane;
            if (lane < 16) {
                const float v2 = row[69 + lane];
                if (v2 > v) { v = v2; ci = 64 + lane; }
            }
            #pragma unroll
            for (int off = 32; off > 0; off >>= 1) {
                const float ov = __shfl_xor(v, off);
                const int oi = __shfl_xor(ci, off);
                if (ov > v || (ov == v && oi < ci)) { v = ov; ci = oi; }
            }
            const float cx = row[0], cy = row[1], w = row[2], h = row[3];
            const float hw = w * 0.5f, hh = h * 0.5f;
            x1 = cx - hw; y1 = cy - hh; x2 = cx + hw; y2 = cy + hh;
            clsf = (float)ci;
        }
        if (lane == 0) {
            const float off = clsf * CLS_OFF;
            const float X1 = x1 + off, Y1 = y1 + off, X2 = x2 + off, Y2 = y2 + off;
            nx1[r] = X1; ny1[r] = Y1; nx2[r] = X2; ny2[r] = Y2;
            nar[r] = (X2 - X1) * (Y2 - Y1);
            detL[r * 6 + 0] = x1; detL[r * 6 + 1] = y1;
            detL[r * 6 + 2] = x2; detL[r * 6 + 3] = y2;
            detL[r * 6 + 4] = okrow ? conf : 0.0f;
            detL[r * 6 + 5] = clsf;
            val[r] = okrow ? 1 : 0;
        }
    }
    __syncthreads();

    // ---- valid bits -> 8 keep words ----
    if (tid < TOPK) {
        const unsigned long long vb = __ballot(val[tid] != 0);
        if (lane == 0) kw8[wv] = vb;
    }
    __syncthreads();

    // ---- IoU > thre bitmask (j > i only) ----
    for (int p = tid; p < TOPK * TOPK; p += 1024) {
        const int i = p >> 9;
        const int j = p & (TOPK - 1);
        bool sup = false;
        if (j > i) {
            const float xx1 = fmaxf(nx1[i], nx1[j]);
            const float yy1 = fmaxf(ny1[i], ny1[j]);
            const float xx2 = fminf(nx2[i], nx2[j]);
            const float yy2 = fminf(ny2[i], ny2[j]);
            const float iw = fmaxf(xx2 - xx1, 0.0f);
            const float ih = fmaxf(yy2 - yy1, 0.0f);
            const float inter = iw * ih;
            const float uni = nar[i] + nar[j] - inter;
            const float iou = inter / uni;       // IEEE div; NaN>thre == false
            sup = iou > NMS_THRE;
        }
        const unsigned long long bmm = __ballot(sup);
        if (lane == 0) sh.mask[p >> 6] = bmm;    // p>>6 == i*8 + (j>>6)
    }
    __syncthreads();

    // ---- sequential greedy on one wave ----
    if (wv == 0) {
        unsigned long long kw = (lane < 8) ? kw8[lane] : 0ull;
        for (int i = 0; i < TOPK; ++i) {
            const unsigned long long w = __shfl(kw, i >> 6);
            if ((w >> (i & 63)) & 1ull) {
                if (lane < 8) kw &= ~sh.mask[i * 8 + lane];
            }
        }
        if (lane < 8) kw8[lane] = kw;
    }
    __syncthreads();

    // ---- outputs ----
    float* det_out = out + (size_t)img * (TOPK * 6);
    float* keep_out = out + (size_t)BATCH * TOPK * 6 + (size_t)img * TOPK;
    for (int idx = tid; idx < TOPK * 6; idx += 1024) {
        const int r = idx / 6;
        const float kf = ((kw8[r >> 6] >> (r & 63)) & 1ull) ? 1.0f : 0.0f;
        det_out[idx] = detL[idx] * kf;
    }
    for (int r = tid; r < TOPK; r += 1024) {
        keep_out[r] = ((kw8[r >> 6] >> (r & 63)) & 1ull) ? 1.0f : 0.0f;
    }
}

extern "C" void kernel_launch(void* const* d_in, const int* in_sizes, int n_in,
                              void* d_out, int out_size, void* d_ws, size_t ws_size,
                              hipStream_t stream) {
    const float* pred = (const float*)d_in[0];
    float* out = (float*)d_out;
    int* cnt = (int*)d_ws;
    unsigned long long* cand = (unsigned long long*)((char*)d_ws + 128);

    hipMemsetAsync(d_ws, 0, 128, stream);   // zero the 32 per-image counters

    dim3 g1((NANCH + 127) / 128, BATCH);
    scan_kernel<<<g1, 128, 0, stream>>>(pred, cand, cnt);
    select_nms_kernel<<<BATCH, 1024, 0, stream>>>(pred, cand, cnt, out);
}

// Round 2
// 571.346 us; speedup vs baseline: 1.1208x; 1.1208x over previous
//
#include <hip/hip_runtime.h>
#include <stdint.h>

#define BATCH 32
#define NANCH 25200
#define CH 85
#define NCLS 80
#define TOPK 512
#define CONF_THRE 0.7f
#define NMS_THRE 0.45f
#define CLS_OFF 4096.0f
#define CANDCAP 16384          // expected valid/img ~7560; +120 sigma margin

typedef unsigned long long u64;

// ws layout (bytes):
//   [0,128)                 int cnt[32]
//   [128, 128+4194304)      u64 cand[32][CANDCAP]     (reused by masks after k2)
//   [4194432, +327680)      float nms[32][5][512]     x1,y1,x2,y2,area
//   [4522112, +393216)      float det[32][512][6]
//   [4915328, +2048)        u64 valid[32][8]
//   masks: u64 mask[32][512][8] at offset 128 (overlaps cand; written by k3 AFTER k2 consumed cand)

#define OFF_CAND   128
#define OFF_NMS    4194432
#define OFF_DET    4522112
#define OFF_VALID  4915328
#define OFF_MASK   128

// ---------------- scan: conf = obj * max(cls); emit key64 per candidate ----------------
// key64 = (conf_bits << 32) | (0xFFFFFFFF - anchor) -> desc sort = conf desc, ties idx asc
__global__ __launch_bounds__(256) void scan_kernel(const float* __restrict__ pred,
                                                   u64* __restrict__ cand,
                                                   int* __restrict__ cnt) {
    __shared__ float tile[64 * CH];     // 21760 B -> 7 blocks/CU
    __shared__ float pmax[4 * 64];
    const int img = blockIdx.y;
    const int a0 = blockIdx.x * 64;
    const int na = min(64, NANCH - a0);
    const int tid = threadIdx.x;
    const int lane = tid & 63;
    const int wv = tid >> 6;
    const float* src = pred + ((size_t)img * NANCH + a0) * CH;
    const int nf = na * CH;
    const int nv = nf >> 2;             // na divisible by 4 -> exact
    const float4* src4 = (const float4*)src;
    float4* t4 = (float4*)tile;
    for (int i = tid; i < nv; i += 256) t4[i] = src4[i];
    for (int i = (nv << 2) + tid; i < nf; i += 256) tile[i] = src[i];
    __syncthreads();

    // each wave computes max over 20 of the 80 class columns for all 64 anchors
    {
        const float* row = tile + lane * CH + 5 + wv * 20;
        float m = row[0];
        #pragma unroll
        for (int j = 1; j < 20; ++j) m = fmaxf(m, row[j]);
        pmax[wv * 64 + lane] = m;
    }
    __syncthreads();

    if (wv == 0) {
        float conf = -1.0f;
        if (lane < na) {
            const float m = fmaxf(fmaxf(pmax[lane], pmax[64 + lane]),
                                  fmaxf(pmax[128 + lane], pmax[192 + lane]));
            conf = tile[lane * CH + 4] * m;
        }
        const bool ok = (lane < na) && (conf >= CONF_THRE);
        const u64 bm = __ballot(ok);
        if (bm) {
            const int leader = __ffsll(bm) - 1;
            int base = 0;
            if (lane == leader) base = atomicAdd(&cnt[img], __popcll(bm));
            base = __shfl(base, leader);
            if (ok) {
                const int rank = __popcll(bm & ((1ull << lane) - 1ull));
                const int pos = base + rank;
                if (pos < CANDCAP) {
                    const unsigned int anchor = (unsigned int)(a0 + lane);
                    const u64 key = ((u64)__float_as_uint(conf) << 32) |
                                    (u64)(0xFFFFFFFFu - anchor);
                    cand[(size_t)img * CANDCAP + pos] = key;
                }
            }
        }
    }
}

// ---------------- k2: exact top-512 (radix select + bitonic sort) + gather ----------------
__global__ __launch_bounds__(1024) void select_kernel(const float* __restrict__ pred,
                                                      const u64* __restrict__ cand,
                                                      const int* __restrict__ cnt,
                                                      float* __restrict__ nmsG,
                                                      float* __restrict__ detG,
                                                      u64* __restrict__ validG) {
    __shared__ u64 sbuf[1024];                      // 8 KB
    __shared__ unsigned int hist[256];
    __shared__ unsigned int sscan[256];
    __shared__ unsigned int s_cnt, s_pivot, s_rem;
    __shared__ unsigned char val[TOPK];

    const int img = blockIdx.x;
    const int tid = threadIdx.x;
    const int lane = tid & 63;
    const int wv = tid >> 6;
    int n = cnt[img];
    if (n > CANDCAP) n = CANDCAP;
    const u64* cd = cand + (size_t)img * CANDCAP;

    // radix select the exact conf bits of the 512th-largest (exp fixed at 126: conf in [0.7,1))
    unsigned int T = 0u;
    if (n > TOPK) {
        unsigned int prefix = 0, pmask = 0, rem = TOPK;
        const int shifts[3] = {15, 7, 0};
        const int nbits[3] = {8, 8, 7};
        for (int p = 0; p < 3; ++p) {
            const int shv = shifts[p];
            const unsigned int nb = 1u << nbits[p];
            if (tid < 256) hist[tid] = 0u;
            __syncthreads();
            for (int i = tid; i < n; i += 1024) {
                unsigned int c = (unsigned int)(cd[i] >> 32) & 0x7FFFFFu;
                if ((c & pmask) == prefix)
                    atomicAdd(&hist[(c >> shv) & (nb - 1u)], 1u);
            }
            __syncthreads();
            if (tid < (int)nb) sscan[tid] = hist[tid];
            __syncthreads();
            for (unsigned int off = 1; off < nb; off <<= 1) {
                unsigned int v = 0;
                if (tid < (int)nb && tid + (int)off < (int)nb) v = sscan[tid + off];
                __syncthreads();
                if (tid < (int)nb) sscan[tid] += v;
                __syncthreads();
            }
            if (tid < (int)nb) {
                unsigned int s = sscan[tid];
                unsigned int snx = (tid + 1 < (int)nb) ? sscan[tid + 1] : 0u;
                if (s >= rem && snx < rem) { s_pivot = (unsigned int)tid; s_rem = rem - snx; }
            }
            __syncthreads();
            prefix |= s_pivot << shv;
            pmask |= (nb - 1u) << shv;
            rem = s_rem;
            __syncthreads();
        }
        T = 0x3F000000u | prefix;
    }

    // compact conf >= T
    if (tid == 0) s_cnt = 0u;
    __syncthreads();
    for (int i = tid; i < n; i += 1024) {
        const u64 k = cd[i];
        if ((unsigned int)(k >> 32) >= T) {
            unsigned int pos = atomicAdd(&s_cnt, 1u);
            if (pos < 1024u) sbuf[pos] = k;
        }
    }
    __syncthreads();
    unsigned int mc = s_cnt; if (mc > 1024u) mc = 1024u;
    if (tid >= (int)mc) sbuf[tid] = 0ull;
    __syncthreads();

    // bitonic sort 1024 desc (key packs conf desc, anchor asc)
    for (int kk = 2; kk <= 1024; kk <<= 1) {
        for (int jj = kk >> 1; jj > 0; jj >>= 1) {
            const int ixj = tid ^ jj;
            if (ixj > tid) {
                const u64 a = sbuf[tid], b = sbuf[ixj];
                const bool up = (tid & kk) == 0;
                if (up ? (a < b) : (a > b)) { sbuf[tid] = b; sbuf[ixj] = a; }
            }
            __syncthreads();
        }
    }

    // gather: one wave per row; argmax with first-max tie rule; write to global
    float* nb_ = nmsG + (size_t)img * (5 * TOPK);
    float* dt_ = detG + (size_t)img * (6 * TOPK);
    for (int r = wv; r < TOPK; r += 16) {
        const u64 key = sbuf[r];
        const float conf = __uint_as_float((unsigned int)(key >> 32));
        const bool okrow = conf >= CONF_THRE;
        float x1 = 0.f, y1 = 0.f, x2 = 0.f, y2 = 0.f, clsf = 0.f;
        if (okrow) {
            const unsigned int anchor = 0xFFFFFFFFu - (unsigned int)(key & 0xFFFFFFFFull);
            const float* row = pred + ((size_t)img * NANCH + anchor) * CH;
            float v = row[5 + lane];
            int ci = lane;
            if (lane < 16) {
                const float v2 = row[69 + lane];
                if (v2 > v) { v = v2; ci = 64 + lane; }
            }
            #pragma unroll
            for (int off = 32; off > 0; off >>= 1) {
                const float ov = __shfl_xor(v, off);
                const int oi = __shfl_xor(ci, off);
                if (ov > v || (ov == v && oi < ci)) { v = ov; ci = oi; }
            }
            const float cx = row[0], cy = row[1], w = row[2], h = row[3];
            const float hw = w * 0.5f, hh = h * 0.5f;
            x1 = cx - hw; y1 = cy - hh; x2 = cx + hw; y2 = cy + hh;
            clsf = (float)ci;
        }
        if (lane == 0) {
            const float off = clsf * CLS_OFF;
            const float X1 = x1 + off, Y1 = y1 + off, X2 = x2 + off, Y2 = y2 + off;
            nb_[0 * TOPK + r] = X1; nb_[1 * TOPK + r] = Y1;
            nb_[2 * TOPK + r] = X2; nb_[3 * TOPK + r] = Y2;
            nb_[4 * TOPK + r] = (X2 - X1) * (Y2 - Y1);
            dt_[r * 6 + 0] = x1; dt_[r * 6 + 1] = y1;
            dt_[r * 6 + 2] = x2; dt_[r * 6 + 3] = y2;
            dt_[r * 6 + 4] = okrow ? conf : 0.0f;
            dt_[r * 6 + 5] = clsf;
            val[r] = okrow ? 1 : 0;
        }
    }
    __syncthreads();

    if (tid < TOPK) {
        const u64 vb = __ballot(val[tid] != 0);
        if (lane == 0) validG[img * 8 + wv] = vb;
    }
}

// ---------------- k3: IoU > thre bitmask, full-chip parallel ----------------
__global__ __launch_bounds__(256) void iou_kernel(const float* __restrict__ nmsG,
                                                  u64* __restrict__ maskG) {
    const int img = blockIdx.x;
    const int slab = blockIdx.y;            // 16 slabs x 32 rows
    const float* nb_ = nmsG + (size_t)img * (5 * TOPK);
    const int lane = threadIdx.x & 63;
    const int q0 = slab * (32 * TOPK);
    for (int q = q0 + threadIdx.x; q < q0 + 32 * TOPK; q += 256) {
        const int i = q >> 9;
        const int j = q & (TOPK - 1);
        bool sup = false;
        if (j > i) {
            const float xx1 = fmaxf(nb_[i], nb_[j]);
            const float yy1 = fmaxf(nb_[TOPK + i], nb_[TOPK + j]);
            const float xx2 = fminf(nb_[2 * TOPK + i], nb_[2 * TOPK + j]);
            const float yy2 = fminf(nb_[3 * TOPK + i], nb_[3 * TOPK + j]);
            const float iw = fmaxf(xx2 - xx1, 0.0f);
            const float ih = fmaxf(yy2 - yy1, 0.0f);
            const float inter = iw * ih;
            const float uni = nb_[4 * TOPK + i] + nb_[4 * TOPK + j] - inter;
            const float iou = inter / uni;   // IEEE div, matches ref; NaN>thre == false
            sup = iou > NMS_THRE;
        }
        const u64 bm = __ballot(sup);
        if (lane == 0) maskG[(size_t)img * 4096 + (q >> 6)] = bm;
    }
}

// ---------------- k4: sequential greedy NMS (mask in LDS) + output ----------------
__global__ __launch_bounds__(256) void greedy_kernel(const u64* __restrict__ maskG,
                                                     const u64* __restrict__ validG,
                                                     const float* __restrict__ detG,
                                                     float* __restrict__ out) {
    __shared__ u64 m[TOPK * 8];     // 32 KB
    __shared__ u64 kw8[8];
    const int img = blockIdx.x;
    const int tid = threadIdx.x;
    const int lane = tid & 63;
    const int wv = tid >> 6;
    const u64* mg = maskG + (size_t)img * 4096;
    for (int i = tid; i < 4096; i += 256) m[i] = mg[i];
    __syncthreads();

    if (wv == 0) {
        u64 kw = (lane < 8) ? validG[img * 8 + lane] : 0ull;
        for (int i = 0; i < TOPK; ++i) {
            const u64 w = __shfl(kw, i >> 6);
            if ((w >> (i & 63)) & 1ull) {
                if (lane < 8) kw &= ~m[i * 8 + lane];
            }
        }
        if (lane < 8) kw8[lane] = kw;
    }
    __syncthreads();

    const float* dt_ = detG + (size_t)img * (6 * TOPK);
    float* det_out = out + (size_t)img * (TOPK * 6);
    float* keep_out = out + (size_t)BATCH * TOPK * 6 + (size_t)img * TOPK;
    for (int idx = tid; idx < TOPK * 6; idx += 256) {
        const int r = idx / 6;
        const float kf = ((kw8[r >> 6] >> (r & 63)) & 1ull) ? 1.0f : 0.0f;
        det_out[idx] = dt_[idx] * kf;
    }
    for (int r = tid; r < TOPK; r += 256) {
        keep_out[r] = ((kw8[r >> 6] >> (r & 63)) & 1ull) ? 1.0f : 0.0f;
    }
}

extern "C" void kernel_launch(void* const* d_in, const int* in_sizes, int n_in,
                              void* d_out, int out_size, void* d_ws, size_t ws_size,
                              hipStream_t stream) {
    const float* pred = (const float*)d_in[0];
    float* out = (float*)d_out;
    char* ws = (char*)d_ws;
    int* cnt = (int*)ws;
    u64* cand = (u64*)(ws + OFF_CAND);
    float* nmsG = (float*)(ws + OFF_NMS);
    float* detG = (float*)(ws + OFF_DET);
    u64* validG = (u64*)(ws + OFF_VALID);
    u64* maskG = (u64*)(ws + OFF_MASK);   // overlaps cand: written only after k2 consumed cand

    hipMemsetAsync(ws, 0, 128, stream);

    dim3 g1((NANCH + 63) / 64, BATCH);
    scan_kernel<<<g1, 256, 0, stream>>>(pred, cand, cnt);
    select_kernel<<<BATCH, 1024, 0, stream>>>(pred, cand, cnt, nmsG, detG, validG);
    dim3 g3(BATCH, 16);
    iou_kernel<<<g3, 256, 0, stream>>>(nmsG, maskG);
    greedy_kernel<<<BATCH, 256, 0, stream>>>(maskG, validG, detG, out);
}

// Round 3
// 513.637 us; speedup vs baseline: 1.2467x; 1.1124x over previous
//
#include <hip/hip_runtime.h>
#include <stdint.h>

#define BATCH 32
#define NANCH 25200
#define CH 85
#define NCLS 80
#define TOPK 512
#define CONF_THRE 0.7f
#define NMS_THRE 0.45f
#define CLS_OFF 4096.0f

typedef unsigned long long u64;
typedef unsigned int u32;

// ws layout (bytes):
//   [0, 3225600)            u32 conf32[32][25200]   (conf bits, 0 if below threshold)
//   [3225600, +327680)      float nms[32][5][512]   x1,y1,x2,y2,area (class-offset boxes)
//   [3553280, +393216)      float det[32][512][6]
//   [3946496, +2048)        u64 valid[32][8]
//   [3948544, +1048576)     u64 mask[32][512][8]
#define OFF_CONF  0
#define OFF_NMS   3225600
#define OFF_DET   3553280
#define OFF_VALID 3946496
#define OFF_MASK  3948544

// ---------------- scan: conf = obj * max(cls) -> one fixed slot per anchor (NO atomics) ----
__global__ __launch_bounds__(256) void scan_kernel(const float* __restrict__ pred,
                                                   u32* __restrict__ conf32) {
    __shared__ float tile[64 * CH];     // 21760 B -> 7 blocks/CU
    __shared__ float pmax[4 * 64];
    const int img = blockIdx.y;
    const int a0 = blockIdx.x * 64;
    const int na = min(64, NANCH - a0);           // 25200 = 393*64 + 48
    const int tid = threadIdx.x;
    const int lane = tid & 63;
    const int wv = tid >> 6;
    const float* src = pred + ((size_t)img * NANCH + a0) * CH;
    const int nv = (na * CH) >> 2;                // 64*85 and 48*85 both %4==0
    const float4* src4 = (const float4*)src;      // 16B-aligned: offsets are multiples of 16
    float4* t4 = (float4*)tile;
    for (int i = tid; i < nv; i += 256) t4[i] = src4[i];
    __syncthreads();

    // each wave: max over 20 of the 80 class cols for all 64 anchors
    // LDS stride 85 -> bank = lane*21 mod 32, gcd(21,32)=1 -> 2-way only (free)
    {
        const float* row = tile + lane * CH + 5 + wv * 20;
        float m = row[0];
        #pragma unroll
        for (int j = 1; j < 20; ++j) m = fmaxf(m, row[j]);
        pmax[wv * 64 + lane] = m;
    }
    __syncthreads();

    if (wv == 0 && lane < na) {
        const float m = fmaxf(fmaxf(pmax[lane], pmax[64 + lane]),
                              fmaxf(pmax[128 + lane], pmax[192 + lane]));
        const float conf = tile[lane * CH + 4] * m;
        conf32[(size_t)img * NANCH + a0 + lane] =
            (conf >= CONF_THRE) ? __float_as_uint(conf) : 0u;
    }
}

// ---------------- k2: exact top-512 (radix select + rank sort) + gather ----------------
__global__ __launch_bounds__(1024) void select_kernel(const float* __restrict__ pred,
                                                      const u32* __restrict__ conf32,
                                                      float* __restrict__ nmsG,
                                                      float* __restrict__ detG,
                                                      u64* __restrict__ validG) {
    __shared__ u64 sbuf[1024];          // 8 KB  compacted keys (unordered)
    __shared__ u64 sorted[1024];        // 8 KB  rank-scattered keys
    __shared__ u32 hist[256];
    __shared__ u32 wtot[4];
    __shared__ u32 s_cnt, s_pivot, s_rem;
    __shared__ unsigned char val[TOPK];

    const int img = blockIdx.x;
    const int tid = threadIdx.x;
    const int lane = tid & 63;
    const int wv = tid >> 6;
    const u32* cd = conf32 + (size_t)img * NANCH;

    // radix select exact conf bits of the 512th-largest.
    // valid confs are in [0.7,1): exp=126, mantissa >= 0x333333. invalid slots are 0
    // (mantissa 0) and only ever pollute bin 0; if fewer than 512 valid, T degenerates
    // to 0x3F000000 which still selects exactly the valid set.
    unsigned int prefix = 0, pmask = 0, rem = TOPK;
    const int shifts[3] = {15, 7, 0};
    const int nbits[3] = {8, 8, 7};
    for (int p = 0; p < 3; ++p) {
        const int shv = shifts[p];
        const u32 nb = 1u << nbits[p];
        if (tid < (int)nb) hist[tid] = 0u;
        __syncthreads();
        for (int i = tid; i < NANCH; i += 1024) {
            const u32 c = cd[i] & 0x7FFFFFu;
            if ((c & pmask) == prefix)
                atomicAdd(&hist[(c >> shv) & (nb - 1u)], 1u);
        }
        __syncthreads();
        // wave-shuffle inclusive suffix scan over the nb bins (bin = wv*64+lane)
        u32 v = 0, s = 0;
        if (tid < (int)nb) {
            v = hist[tid];
            s = v;
            #pragma unroll
            for (int off = 1; off < 64; off <<= 1) {
                const u32 t = __shfl_down(s, off);
                if (lane + off < 64) s += t;
            }
            if (lane == 0) wtot[wv] = s;
        }
        __syncthreads();
        if (tid < (int)nb) {
            u32 add = 0;
            for (int w2 = wv + 1; w2 < (int)(nb >> 6); ++w2) add += wtot[w2];
            const u32 sfull = s + add;       // count of entries in bins >= tid
            const u32 snext = sfull - v;     // count of entries in bins >  tid
            if (sfull >= rem && snext < rem) { s_pivot = (u32)tid; s_rem = rem - snext; }
        }
        __syncthreads();
        prefix |= s_pivot << shv;
        pmask |= (nb - 1u) << shv;
        rem = s_rem;
        __syncthreads();
    }
    const u32 T = 0x3F000000u | prefix;

    // compact conf >= T (LDS atomic; order irrelevant, rank-sort fixes it)
    if (tid == 0) s_cnt = 0u;
    __syncthreads();
    for (int i = tid; i < NANCH; i += 1024) {
        const u32 c = cd[i];
        if (c >= T) {
            const u32 pos = atomicAdd(&s_cnt, 1u);
            if (pos < 1024u)
                sbuf[pos] = ((u64)c << 32) | (u64)(0xFFFFFFFFu - (u32)i);
        }
    }
    __syncthreads();
    const u32 mc = (s_cnt > 1024u) ? 1024u : s_cnt;

    // rank sort: keys unique (distinct anchors) -> rank = #{key' > key} is a bijection
    sorted[tid] = 0ull;
    u32 rank = 0; u64 my = 0ull;
    if (tid < (int)mc) {
        my = sbuf[tid];
        for (u32 i = 0; i < mc; ++i) rank += (sbuf[i] > my) ? 1u : 0u;
    }
    __syncthreads();
    if (tid < (int)mc) sorted[rank] = my;   // ranks >= 512 land in [512,1024), ignored
    __syncthreads();

    // gather: one wave per row; argmax with first-max tie rule; write to global
    float* nb_ = nmsG + (size_t)img * (5 * TOPK);
    float* dt_ = detG + (size_t)img * (6 * TOPK);
    for (int r = wv; r < TOPK; r += 16) {
        const u64 key = sorted[r];
        const float conf = __uint_as_float((u32)(key >> 32));
        const bool okrow = conf >= CONF_THRE;
        float x1 = 0.f, y1 = 0.f, x2 = 0.f, y2 = 0.f, clsf = 0.f;
        if (okrow) {
            const u32 anchor = 0xFFFFFFFFu - (u32)(key & 0xFFFFFFFFull);
            const float* row = pred + ((size_t)img * NANCH + anchor) * CH;
            float v = row[5 + lane];
            int ci = lane;
            if (lane < 16) {
                const float v2 = row[69 + lane];
                if (v2 > v) { v = v2; ci = 64 + lane; }
            }
            #pragma unroll
            for (int off = 32; off > 0; off >>= 1) {
                const float ov = __shfl_xor(v, off);
                const int oi = __shfl_xor(ci, off);
                if (ov > v || (ov == v && oi < ci)) { v = ov; ci = oi; }
            }
            const float cx = row[0], cy = row[1], w = row[2], h = row[3];
            const float hw = w * 0.5f, hh = h * 0.5f;
            x1 = cx - hw; y1 = cy - hh; x2 = cx + hw; y2 = cy + hh;
            clsf = (float)ci;
        }
        if (lane == 0) {
            const float off = clsf * CLS_OFF;
            const float X1 = x1 + off, Y1 = y1 + off, X2 = x2 + off, Y2 = y2 + off;
            nb_[0 * TOPK + r] = X1; nb_[1 * TOPK + r] = Y1;
            nb_[2 * TOPK + r] = X2; nb_[3 * TOPK + r] = Y2;
            nb_[4 * TOPK + r] = (X2 - X1) * (Y2 - Y1);
            dt_[r * 6 + 0] = x1; dt_[r * 6 + 1] = y1;
            dt_[r * 6 + 2] = x2; dt_[r * 6 + 3] = y2;
            dt_[r * 6 + 4] = okrow ? conf : 0.0f;
            dt_[r * 6 + 5] = clsf;
            val[r] = okrow ? 1 : 0;
        }
    }
    __syncthreads();

    if (tid < TOPK) {
        const u64 vb = __ballot(val[tid] != 0);
        if (lane == 0) validG[img * 8 + wv] = vb;
    }
}

// ---------------- k3: IoU > thre bitmask, full-chip parallel, boxes staged in LDS ----------
__global__ __launch_bounds__(256) void iou_kernel(const float* __restrict__ nmsG,
                                                  u64* __restrict__ maskG) {
    __shared__ float bx1[TOPK], by1[TOPK], bx2[TOPK], by2[TOPK], bar[TOPK];  // 10 KB
    const int img = blockIdx.x;
    const int slab = blockIdx.y;            // 16 slabs x 32 rows each
    const int tid = threadIdx.x;
    const int lane = tid & 63;
    const float* nb_ = nmsG + (size_t)img * (5 * TOPK);
    for (int i = tid; i < TOPK; i += 256) {
        bx1[i] = nb_[i];            by1[i] = nb_[TOPK + i];
        bx2[i] = nb_[2 * TOPK + i]; by2[i] = nb_[3 * TOPK + i];
        bar[i] = nb_[4 * TOPK + i];
    }
    __syncthreads();
    const int q0 = slab * (32 * TOPK);
    for (int q = q0 + tid; q < q0 + 32 * TOPK; q += 256) {
        const int i = q >> 9;               // uniform within wave -> LDS broadcast
        const int j = q & (TOPK - 1);       // lane-consecutive -> conflict-free
        bool sup = false;
        if (j > i) {
            const float xx1 = fmaxf(bx1[i], bx1[j]);
            const float yy1 = fmaxf(by1[i], by1[j]);
            const float xx2 = fminf(bx2[i], bx2[j]);
            const float yy2 = fminf(by2[i], by2[j]);
            const float iw = fmaxf(xx2 - xx1, 0.0f);
            const float ih = fmaxf(yy2 - yy1, 0.0f);
            const float inter = iw * ih;
            const float uni = bar[i] + bar[j] - inter;
            const float iou = inter / uni;  // IEEE div, NaN>thre == false (matches ref)
            sup = iou > NMS_THRE;
        }
        const u64 bm = __ballot(sup);
        if (lane == 0) maskG[(size_t)img * 4096 + (q >> 6)] = bm;
    }
}

// ---------------- k4: sequential greedy NMS (mask in LDS) + output ----------------
__global__ __launch_bounds__(256) void greedy_kernel(const u64* __restrict__ maskG,
                                                     const u64* __restrict__ validG,
                                                     const float* __restrict__ detG,
                                                     float* __restrict__ out) {
    __shared__ u64 m[TOPK * 8];     // 32 KB
    __shared__ u64 kw8[8];
    const int img = blockIdx.x;
    const int tid = threadIdx.x;
    const int lane = tid & 63;
    const int wv = tid >> 6;
    const u64* mg = maskG + (size_t)img * 4096;
    for (int i = tid; i < 4096; i += 256) m[i] = mg[i];
    __syncthreads();

    if (wv == 0) {
        u64 kw = (lane < 8) ? validG[img * 8 + lane] : 0ull;
        for (int i = 0; i < TOPK; ++i) {
            const u64 w = __shfl(kw, i >> 6);
            if ((w >> (i & 63)) & 1ull) {
                if (lane < 8) kw &= ~m[i * 8 + lane];
            }
        }
        if (lane < 8) kw8[lane] = kw;
    }
    __syncthreads();

    const float* dt_ = detG + (size_t)img * (6 * TOPK);
    float* det_out = out + (size_t)img * (TOPK * 6);
    float* keep_out = out + (size_t)BATCH * TOPK * 6 + (size_t)img * TOPK;
    for (int idx = tid; idx < TOPK * 6; idx += 256) {
        const int r = idx / 6;
        const float kf = ((kw8[r >> 6] >> (r & 63)) & 1ull) ? 1.0f : 0.0f;
        det_out[idx] = dt_[idx] * kf;
    }
    for (int r = tid; r < TOPK; r += 256) {
        keep_out[r] = ((kw8[r >> 6] >> (r & 63)) & 1ull) ? 1.0f : 0.0f;
    }
}

extern "C" void kernel_launch(void* const* d_in, const int* in_sizes, int n_in,
                              void* d_out, int out_size, void* d_ws, size_t ws_size,
                              hipStream_t stream) {
    const float* pred = (const float*)d_in[0];
    float* out = (float*)d_out;
    char* ws = (char*)d_ws;
    u32* conf32 = (u32*)(ws + OFF_CONF);
    float* nmsG = (float*)(ws + OFF_NMS);
    float* detG = (float*)(ws + OFF_DET);
    u64* validG = (u64*)(ws + OFF_VALID);
    u64* maskG = (u64*)(ws + OFF_MASK);

    dim3 g1((NANCH + 63) / 64, BATCH);
    scan_kernel<<<g1, 256, 0, stream>>>(pred, conf32);
    select_kernel<<<BATCH, 1024, 0, stream>>>(pred, conf32, nmsG, detG, validG);
    dim3 g3(BATCH, 16);
    iou_kernel<<<g3, 256, 0, stream>>>(nmsG, maskG);
    greedy_kernel<<<BATCH, 256, 0, stream>>>(maskG, validG, detG, out);
}

// Round 4
// 483.579 us; speedup vs baseline: 1.3242x; 1.0622x over previous
//
#include <hip/hip_runtime.h>
#include <stdint.h>

#define BATCH 32
#define NANCH 25200
#define CH 85
#define NCLS 80
#define TOPK 512
#define CONF_THRE 0.7f
#define NMS_THRE 0.45f
#define CLS_OFF 4096.0f
#define NCHUNK 25
#define CHUNK 1008

typedef unsigned long long u64;
typedef unsigned int u32;

// ws layout (bytes):
//   [0, 3225600)          u32 conf32[32][25200]    (conf bits, 0 if below threshold)
//   [3225600, +819200)    u32 hist[32][25][256]    per-chunk histograms (no atomics)
//   [4044800, +327680)    float nms[32][5][512]    x1,y1,x2,y2,area (class-offset)
//   [4372480, +393216)    float det[32][512][6]
//   [4765696, +2048)      u64 valid[32][8]
//   [4767744, +1048576)   u64 mask[32][512][8]
#define OFF_CONF  0
#define OFF_HIST  3225600
#define OFF_NMS   4044800
#define OFF_DET   4372480
#define OFF_VALID 4765696
#define OFF_MASK  4767744

// ---- k1 scan: wave-transposed, no LDS, no barriers. 16 lanes per anchor. ----
__global__ __launch_bounds__(256) void scan_kernel(const float* __restrict__ pred,
                                                   u32* __restrict__ conf32) {
    const int tid = threadIdx.x;
    const int lane = tid & 63;
    const int wv = tid >> 6;
    const int g = lane >> 4;          // anchor-in-wave 0..3
    const int l = lane & 15;          // lane-in-group
    const int a = blockIdx.x * 16 + wv * 4 + g;     // flat img*NANCH+anchor
    const size_t base = (size_t)a * CH;

    float m = -1.0f, obj = 0.0f;
    {   // p = l*4 .. l*4+3  (covers 0..63)
        const float4 q = *(const float4*)(pred + base + (l << 2));
        const int p = l << 2;
        if (p + 0 >= 5) m = fmaxf(m, q.x); else if (p + 0 == 4) obj = q.x;
        if (p + 1 >= 5) m = fmaxf(m, q.y); else if (p + 1 == 4) obj = q.y;
        if (p + 2 >= 5) m = fmaxf(m, q.z); else if (p + 2 == 4) obj = q.z;
        if (p + 3 >= 5) m = fmaxf(m, q.w); else if (p + 3 == 4) obj = q.w;
    }
    if (l < 5) {                      // p = 64 .. 83 (all classes)
        const float4 q = *(const float4*)(pred + base + 64 + (l << 2));
        m = fmaxf(fmaxf(m, fmaxf(q.x, q.y)), fmaxf(q.z, q.w));
    } else if (l == 5) {              // p = 84
        m = fmaxf(m, pred[base + 84]);
    }
    #pragma unroll
    for (int off = 1; off < 16; off <<= 1) m = fmaxf(m, __shfl_xor(m, off));
    const float ob = __shfl(obj, (lane & 48) + 1);  // lane g*16+1 holds p==4
    const float conf = ob * m;
    if (l == 0)
        conf32[a] = (conf >= CONF_THRE) ? __float_as_uint(conf) : 0u;
}

// ---- k2 hist: per-(img,chunk) 256-bin histogram of top-8 mantissa bits ----
__global__ __launch_bounds__(256) void hist_kernel(const u32* __restrict__ conf32,
                                                   u32* __restrict__ histG) {
    __shared__ u32 h[256];
    const int img = blockIdx.x, chunk = blockIdx.y, tid = threadIdx.x;
    h[tid] = 0u;
    __syncthreads();
    const u32* cd = conf32 + (size_t)img * NANCH + chunk * CHUNK;
    for (int i = tid; i < CHUNK; i += 256) {
        const u32 c = cd[i];
        if (c) atomicAdd(&h[(c >> 15) & 255u], 1u);   // valid bins are 102..255
    }
    __syncthreads();
    histG[((size_t)img * NCHUNK + chunk) * 256 + tid] = h[tid];
}

// ---- k3: threshold from hist + single-pass compact + rank sort + gather ----
__global__ __launch_bounds__(1024) void select_kernel(const float* __restrict__ pred,
                                                      const u32* __restrict__ conf32,
                                                      const u32* __restrict__ histG,
                                                      float* __restrict__ nmsG,
                                                      float* __restrict__ detG,
                                                      u64* __restrict__ validG) {
    __shared__ u64 sbuf[1024];
    __shared__ u64 sorted[1024];
    __shared__ u32 hist[256];
    __shared__ u32 wtot[4];
    __shared__ u32 s_cnt, s_pivot;
    __shared__ unsigned char val[TOPK];

    const int img = blockIdx.x;
    const int tid = threadIdx.x;
    const int lane = tid & 63;
    const int wv = tid >> 6;

    if (tid == 0) { s_cnt = 0u; s_pivot = 0u; }   // pivot 0 => T=0x3F000000 selects all valid
    if (tid < 256) {
        const u32* hsrc = histG + (size_t)img * (NCHUNK * 256) + tid;
        u32 s0 = 0;
        #pragma unroll
        for (int c = 0; c < NCHUNK; ++c) s0 += hsrc[c * 256];
        hist[tid] = s0;
    }
    __syncthreads();
    // inclusive suffix scan over 256 bins (4 waves + cross-wave totals)
    u32 v = 0, s = 0;
    if (tid < 256) {
        v = hist[tid]; s = v;
        #pragma unroll
        for (int off = 1; off < 64; off <<= 1) {
            const u32 t = __shfl_down(s, off);
            if (lane + off < 64) s += t;
        }
        if (lane == 0) wtot[wv] = s;
    }
    __syncthreads();
    if (tid < 256) {
        u32 add = 0;
        for (int w2 = wv + 1; w2 < 4; ++w2) add += wtot[w2];
        const u32 sfull = s + add;        // count in bins >= tid
        const u32 snext = sfull - v;      // count in bins >  tid
        if (sfull >= TOPK && snext < TOPK) s_pivot = (u32)tid;
    }
    __syncthreads();
    const u32 T = 0x3F000000u | (s_pivot << 15);

    // single-pass compact conf >= T (order-free; rank sort restores exact order)
    const u32* cd = conf32 + (size_t)img * NANCH;
    for (int i = tid; i < NANCH; i += 1024) {
        const u32 c = cd[i];
        if (c >= T) {
            const u32 pos = atomicAdd(&s_cnt, 1u);
            if (pos < 1024u)
                sbuf[pos] = ((u64)c << 32) | (u64)(0xFFFFFFFFu - (u32)i);
        }
    }
    __syncthreads();
    const u32 mc = (s_cnt > 1024u) ? 1024u : s_cnt;

    // rank sort (keys unique by anchor): rank = #{key' > key}
    sorted[tid] = 0ull;
    u32 rank = 0; u64 my = 0ull;
    if (tid < (int)mc) {
        my = sbuf[tid];
        for (u32 i = 0; i < mc; ++i) rank += (sbuf[i] > my) ? 1u : 0u;
    }
    __syncthreads();
    if (tid < (int)mc && rank < 1024u) sorted[rank] = my;
    __syncthreads();

    // gather: one wave per row; argmax first-max tie rule; write global
    float* nb_ = nmsG + (size_t)img * (5 * TOPK);
    float* dt_ = detG + (size_t)img * (6 * TOPK);
    for (int r = wv; r < TOPK; r += 16) {
        const u64 key = sorted[r];
        const float conf = __uint_as_float((u32)(key >> 32));
        const bool okrow = conf >= CONF_THRE;
        float x1 = 0.f, y1 = 0.f, x2 = 0.f, y2 = 0.f, clsf = 0.f;
        if (okrow) {
            const u32 anchor = 0xFFFFFFFFu - (u32)(key & 0xFFFFFFFFull);
            const float* row = pred + ((size_t)img * NANCH + anchor) * CH;
            float vv = row[5 + lane];
            int ci = lane;
            if (lane < 16) {
                const float v2 = row[69 + lane];
                if (v2 > vv) { vv = v2; ci = 64 + lane; }
            }
            #pragma unroll
            for (int off = 32; off > 0; off >>= 1) {
                const float ov = __shfl_xor(vv, off);
                const int oi = __shfl_xor(ci, off);
                if (ov > vv || (ov == vv && oi < ci)) { vv = ov; ci = oi; }
            }
            const float cx = row[0], cy = row[1], w = row[2], h = row[3];
            const float hw = w * 0.5f, hh = h * 0.5f;
            x1 = cx - hw; y1 = cy - hh; x2 = cx + hw; y2 = cy + hh;
            clsf = (float)ci;
        }
        if (lane == 0) {
            const float off = clsf * CLS_OFF;
            const float X1 = x1 + off, Y1 = y1 + off, X2 = x2 + off, Y2 = y2 + off;
            nb_[0 * TOPK + r] = X1; nb_[1 * TOPK + r] = Y1;
            nb_[2 * TOPK + r] = X2; nb_[3 * TOPK + r] = Y2;
            nb_[4 * TOPK + r] = (X2 - X1) * (Y2 - Y1);
            dt_[r * 6 + 0] = x1; dt_[r * 6 + 1] = y1;
            dt_[r * 6 + 2] = x2; dt_[r * 6 + 3] = y2;
            dt_[r * 6 + 4] = okrow ? conf : 0.0f;
            dt_[r * 6 + 5] = clsf;
            val[r] = okrow ? 1 : 0;
        }
    }
    __syncthreads();

    if (tid < TOPK) {
        const u64 vb = __ballot(val[tid] != 0);
        if (lane == 0) validG[img * 8 + wv] = vb;
    }
}

// ---- k4 iou: full-chip bitmask, boxes staged in LDS ----
__global__ __launch_bounds__(256) void iou_kernel(const float* __restrict__ nmsG,
                                                  u64* __restrict__ maskG) {
    __shared__ float bx1[TOPK], by1[TOPK], bx2[TOPK], by2[TOPK], bar[TOPK];
    const int img = blockIdx.x;
    const int slab = blockIdx.y;            // 32 slabs x 16 rows
    const int tid = threadIdx.x;
    const int lane = tid & 63;
    const float* nb_ = nmsG + (size_t)img * (5 * TOPK);
    for (int i = tid; i < TOPK; i += 256) {
        bx1[i] = nb_[i];            by1[i] = nb_[TOPK + i];
        bx2[i] = nb_[2 * TOPK + i]; by2[i] = nb_[3 * TOPK + i];
        bar[i] = nb_[4 * TOPK + i];
    }
    __syncthreads();
    const int q0 = slab * (16 * TOPK);
    for (int q = q0 + tid; q < q0 + 16 * TOPK; q += 256) {
        const int i = q >> 9;               // wave-uniform -> LDS broadcast
        const int j = q & (TOPK - 1);       // lane-consecutive -> conflict-free
        bool sup = false;
        if (j > i) {
            const float xx1 = fmaxf(bx1[i], bx1[j]);
            const float yy1 = fmaxf(by1[i], by1[j]);
            const float xx2 = fminf(bx2[i], bx2[j]);
            const float yy2 = fminf(by2[i], by2[j]);
            const float iw = fmaxf(xx2 - xx1, 0.0f);
            const float ih = fmaxf(yy2 - yy1, 0.0f);
            const float inter = iw * ih;
            const float uni = bar[i] + bar[j] - inter;
            const float iou = inter / uni;  // IEEE div, NaN>thre == false (matches ref)
            sup = iou > NMS_THRE;
        }
        const u64 bm = __ballot(sup);
        if (lane == 0) maskG[(size_t)img * 4096 + (q >> 6)] = bm;
    }
}

// ---- k5 greedy: sequential NMS with 4-deep LDS prefetch, branchless update ----
__global__ __launch_bounds__(256) void greedy_kernel(const u64* __restrict__ maskG,
                                                     const u64* __restrict__ validG,
                                                     const float* __restrict__ detG,
                                                     float* __restrict__ out) {
    __shared__ u64 m[TOPK * 8];     // 32 KB
    __shared__ u64 kw8[8];
    const int img = blockIdx.x;
    const int tid = threadIdx.x;
    const int lane = tid & 63;
    const int wv = tid >> 6;
    const u64* mg = maskG + (size_t)img * 4096;
    for (int i = tid; i < 4096; i += 256) m[i] = mg[i];
    __syncthreads();

    if (wv == 0) {
        const bool ld = lane < 8;
        u64 kw = ld ? validG[img * 8 + lane] : 0ull;
        u64 p0 = ld ? m[0 * 8 + lane] : 0ull;
        u64 p1 = ld ? m[1 * 8 + lane] : 0ull;
        u64 p2 = ld ? m[2 * 8 + lane] : 0ull;
        u64 p3 = ld ? m[3 * 8 + lane] : 0ull;
        for (int i = 0; i < TOPK; i += 4) {
            {
                const u64 w = __shfl(kw, i >> 6);
                const u64 bit = (w >> (i & 63)) & 1ull;
                kw &= ~(p0 & (0ull - bit));
                p0 = (ld && i + 4 < TOPK) ? m[(i + 4) * 8 + lane] : 0ull;
            }
            {
                const u64 w = __shfl(kw, (i + 1) >> 6);
                const u64 bit = (w >> ((i + 1) & 63)) & 1ull;
                kw &= ~(p1 & (0ull - bit));
                p1 = (ld && i + 5 < TOPK) ? m[(i + 5) * 8 + lane] : 0ull;
            }
            {
                const u64 w = __shfl(kw, (i + 2) >> 6);
                const u64 bit = (w >> ((i + 2) & 63)) & 1ull;
                kw &= ~(p2 & (0ull - bit));
                p2 = (ld && i + 6 < TOPK) ? m[(i + 6) * 8 + lane] : 0ull;
            }
            {
                const u64 w = __shfl(kw, (i + 3) >> 6);
                const u64 bit = (w >> ((i + 3) & 63)) & 1ull;
                kw &= ~(p3 & (0ull - bit));
                p3 = (ld && i + 7 < TOPK) ? m[(i + 7) * 8 + lane] : 0ull;
            }
        }
        if (ld) kw8[lane] = kw;
    }
    __syncthreads();

    const float* dt_ = detG + (size_t)img * (6 * TOPK);
    float* det_out = out + (size_t)img * (TOPK * 6);
    float* keep_out = out + (size_t)BATCH * TOPK * 6 + (size_t)img * TOPK;
    for (int idx = tid; idx < TOPK * 6; idx += 256) {
        const int r = idx / 6;
        const float kf = ((kw8[r >> 6] >> (r & 63)) & 1ull) ? 1.0f : 0.0f;
        det_out[idx] = dt_[idx] * kf;
    }
    for (int r = tid; r < TOPK; r += 256) {
        keep_out[r] = ((kw8[r >> 6] >> (r & 63)) & 1ull) ? 1.0f : 0.0f;
    }
}

extern "C" void kernel_launch(void* const* d_in, const int* in_sizes, int n_in,
                              void* d_out, int out_size, void* d_ws, size_t ws_size,
                              hipStream_t stream) {
    const float* pred = (const float*)d_in[0];
    float* out = (float*)d_out;
    char* ws = (char*)d_ws;
    u32* conf32 = (u32*)(ws + OFF_CONF);
    u32* histG = (u32*)(ws + OFF_HIST);
    float* nmsG = (float*)(ws + OFF_NMS);
    float* detG = (float*)(ws + OFF_DET);
    u64* validG = (u64*)(ws + OFF_VALID);
    u64* maskG = (u64*)(ws + OFF_MASK);

    scan_kernel<<<(BATCH * NANCH) / 16, 256, 0, stream>>>(pred, conf32);
    dim3 g2(BATCH, NCHUNK);
    hist_kernel<<<g2, 256, 0, stream>>>(conf32, histG);
    select_kernel<<<BATCH, 1024, 0, stream>>>(pred, conf32, histG, nmsG, detG, validG);
    dim3 g4(BATCH, 32);
    iou_kernel<<<g4, 256, 0, stream>>>(nmsG, maskG);
    greedy_kernel<<<BATCH, 256, 0, stream>>>(maskG, validG, detG, out);
}